// Round 19
// baseline (1203.696 us; speedup 1.0000x reference)
//
#include <hip/hip_runtime.h>
#include <hip/hip_bf16.h>

#define N_NODES 50000
#define N_EDGES 600000
#define CH 128
#define N_LAYERS 15
#define GB 391                      // gemm grid: 128-row tiles
#define LAP_BLOCKS 2048

typedef float f32x4 __attribute__((ext_vector_type(4)));
typedef short s16x8 __attribute__((ext_vector_type(8)));
typedef unsigned short u16x4 __attribute__((ext_vector_type(4)));
typedef int i32x2 __attribute__((ext_vector_type(2)));

#define LD8(p) (*(const s16x8*)(p))

__device__ __forceinline__ float eluf(float v) {
    return v > 0.f ? v : (__expf(v) - 1.f);
}
__device__ __forceinline__ unsigned short f2bf(float f) {
    unsigned int u = __float_as_uint(f);
    unsigned int r = (u + 0x7FFFu + ((u >> 16) & 1u)) >> 16;
    return (unsigned short)r;
}
__device__ __forceinline__ float bf2f(unsigned short h) {
    return __uint_as_float(((unsigned int)h) << 16);
}
__device__ __forceinline__ void gload_lds16(const unsigned short* g, unsigned short* l) {
    __builtin_amdgcn_global_load_lds(
        (const __attribute__((address_space(1))) unsigned int*)g,
        (__attribute__((address_space(3))) unsigned int*)l, 16, 0, 0);
}

// ---------------- conv1: writes x fp32 + single-bf16 elu plane ----------------
__global__ __launch_bounds__(256) void conv1_kernel(
    const float* __restrict__ in, const float* __restrict__ W1,
    const float* __restrict__ b1, float* __restrict__ x,
    unsigned short* __restrict__ hbh, int n)
{
    int idx = blockIdx.x * blockDim.x + threadIdx.x;
    if (idx >= n * CH) return;
    int node = idx >> 7;
    int c = idx & 127;
    float o = b1[c]
            + in[(size_t)node * 3 + 0] * W1[0 * CH + c]
            + in[(size_t)node * 3 + 1] * W1[1 * CH + c]
            + in[(size_t)node * 3 + 2] * W1[2 * CH + c];
    x[idx] = o;
    hbh[idx] = f2bf(eluf(o));
}

// ---------------- combined zero helper ----------------
__global__ __launch_bounds__(256) void zero_all_kernel(
    int* __restrict__ pi, int ni, float* __restrict__ pf, int nf)
{
    int i = blockIdx.x * blockDim.x + threadIdx.x;
    if (i < ni) pi[i] = 0;
    if (i < nf) pf[i] = 0.f;
}

// ---------------- CSR build ----------------
__global__ __launch_bounds__(256) void count_kernel(
    const int* __restrict__ row, int* __restrict__ cnt, int e)
{
    int i = blockIdx.x * blockDim.x + threadIdx.x;
    if (i < e) atomicAdd(&cnt[row[i]], 1);
}

__global__ __launch_bounds__(1024) void block_reduce_kernel(
    const int* __restrict__ cnt, int* __restrict__ bsum, int n)
{
    __shared__ int sd[1024];
    int tid = threadIdx.x;
    int i = blockIdx.x * 1024 + tid;
    sd[tid] = (i < n) ? cnt[i] : 0;
    __syncthreads();
    for (int off = 512; off > 0; off >>= 1) {
        if (tid < off) sd[tid] += sd[tid + off];
        __syncthreads();
    }
    if (tid == 0) bsum[blockIdx.x] = sd[0];
}

__global__ __launch_bounds__(64) void scan_small_kernel(
    const int* __restrict__ bsum, int* __restrict__ boff, int nb)
{
    int lane = threadIdx.x;
    int orig = (lane < nb) ? bsum[lane] : 0;
    int v = orig;
#pragma unroll
    for (int d = 1; d < 64; d <<= 1) {
        int t = __shfl_up(v, d, 64);
        if (lane >= d) v += t;
    }
    if (lane < nb) boff[lane] = v - orig;  // exclusive
}

__global__ __launch_bounds__(1024) void block_scan_kernel(
    const int* __restrict__ cnt, const int* __restrict__ boff,
    int* __restrict__ row_ptr, int n)
{
    __shared__ int sd[1024];
    int tid = threadIdx.x;
    int i = blockIdx.x * 1024 + tid;
    sd[tid] = (i < n) ? cnt[i] : 0;
    __syncthreads();
    for (int off = 1; off < 1024; off <<= 1) {
        int t = (tid >= off) ? sd[tid - off] : 0;
        __syncthreads();
        sd[tid] += t;
        __syncthreads();
    }
    if (i < n) row_ptr[i + 1] = sd[tid] + boff[blockIdx.x];
    if (i == 0) row_ptr[0] = 0;
}

// cv[dst] = {col byte-offset, val bits} — one 8B scatter per edge
__global__ __launch_bounds__(256) void fill_kernel(
    const int* __restrict__ row, const int* __restrict__ col,
    const float* __restrict__ val, int* __restrict__ cursor,
    const int* __restrict__ row_ptr, i32x2* __restrict__ cv, int e)
{
    int i = blockIdx.x * blockDim.x + threadIdx.x;
    if (i >= e) return;
    int r = row[i];
    int pos = atomicAdd(&cursor[r], 1);
    int dst = row_ptr[r] + pos;
    i32x2 v = { col[i] << 8, __float_as_int(val[i]) };
    cv[dst] = v;
}

// ---------------- mask denominator ----------------
__global__ __launch_bounds__(256) void mask_sum_kernel(
    const float* __restrict__ mask, float* __restrict__ denom, int n)
{
    __shared__ float sd[256];
    int tid = threadIdx.x;
    float s = 0.f;
    for (int i = blockIdx.x * 256 + tid; i < n; i += gridDim.x * 256) s += mask[i];
    sd[tid] = s;
    __syncthreads();
    for (int off = 128; off > 0; off >>= 1) {
        if (tid < off) sd[tid] += sd[tid + off];
        __syncthreads();
    }
    if (tid == 0) atomicAdd(denom, sd[0]);
}

// ---- W pre-split into MFMA-fragment order — HI PLANE ONLY (R14 win) ----
__global__ __launch_bounds__(256) void split_w_kernel(
    const float* __restrict__ W, unsigned short* __restrict__ Wf, int total)
{
    int id = blockIdx.x * 256 + threadIdx.x;
    if (id >= total) return;
    int s = id >> 15;
    int rem = id & 32767;
    int k = rem >> 7;
    int nn = rem & 127;
    unsigned short hi = f2bf(W[id]);
    int c   = k >> 5;
    int kin = k & 31;
    int q   = kin >> 3;
    int ko  = kin & 7;
    int nt  = nn >> 4;
    int c16 = nn & 15;
    int lane = q * 16 + c16;
    size_t base = (size_t)s * 32768 + (size_t)c * 4096 + (size_t)nt * 512
                + (size_t)lane * 8 + ko;
    Wf[base] = hi;
}

// ---- 4-edge gather+FMA for one row (full 256B row per edge, R18 scheme) ----
__device__ __forceinline__ void lap4(
    const i32x2* __restrict__ cv, int t, const char* hbase, int b4,
    float& a0, float& a1)
{
    i32x2 e0 = cv[t], e1 = cv[t + 1], e2 = cv[t + 2], e3 = cv[t + 3];
    unsigned int u0 = *(const unsigned int*)(hbase + e0.x + b4);
    unsigned int u1 = *(const unsigned int*)(hbase + e1.x + b4);
    unsigned int u2 = *(const unsigned int*)(hbase + e2.x + b4);
    unsigned int u3 = *(const unsigned int*)(hbase + e3.x + b4);
    float v0 = __int_as_float(e0.y), v1 = __int_as_float(e1.y);
    float v2 = __int_as_float(e2.y), v3 = __int_as_float(e3.y);
    a0 += v0 * bf2f((unsigned short)u0) + v1 * bf2f((unsigned short)u1)
        + v2 * bf2f((unsigned short)u2) + v3 * bf2f((unsigned short)u3);
    a1 += v0 * bf2f((unsigned short)(u0 >> 16)) + v1 * bf2f((unsigned short)(u1 >> 16))
        + v2 * bf2f((unsigned short)(u2 >> 16)) + v3 * bf2f((unsigned short)(u3 >> 16));
}

// ---------------- Laplacian: prop[row,:] = sum_e val * hb[col,:]
// R18: one wave per row, single 256B VMEM per edge. R19: TWO-ROW INTERLEAVE —
// each wave processes rows (u, u+8192) with independent gather chains,
// doubling per-wave memory-level parallelism (lap was latency-chain bound:
// ~6 serial rows x ~2 gather batches with in-order vmcnt). Control flow stays
// wave-uniform (row bounds are wave-scalar).
__global__ __launch_bounds__(256) void lap_kernel(
    const int* __restrict__ rp, const i32x2* __restrict__ cv,
    const unsigned short* __restrict__ hb,
    unsigned short* __restrict__ ph, int n)
{
    const int unit = (blockIdx.x * 256 + threadIdx.x) >> 6;  // 0..8191
    const int lane = threadIdx.x & 63;
    const int b4 = lane << 2;
    const char* hbase = (const char*)hb;
    const int U = LAP_BLOCKS * 4;                            // 8192
    for (int rowA = unit; rowA < n; rowA += 2 * U) {
        int rowB = rowA + U;
        const bool hasB = (rowB < n);
        int sA = rp[rowA], eA = rp[rowA + 1];
        int sB = 0, eB = 0;
        if (hasB) { sB = rp[rowB]; eB = rp[rowB + 1]; }
        float a0 = 0.f, a1 = 0.f, c0 = 0.f, c1 = 0.f;
        int tA = sA, tB = sB;
        // interleaved phase: two independent 4-edge chains per iteration
        while (tA + 4 <= eA && tB + 4 <= eB) {
            lap4(cv, tA, hbase, b4, a0, a1);
            lap4(cv, tB, hbase, b4, c0, c1);
            tA += 4; tB += 4;
        }
        for (; tA + 4 <= eA; tA += 4) lap4(cv, tA, hbase, b4, a0, a1);
        for (; tB + 4 <= eB; tB += 4) lap4(cv, tB, hbase, b4, c0, c1);
        for (; tA < eA; ++tA) {
            i32x2 ee = cv[tA];
            unsigned int u = *(const unsigned int*)(hbase + ee.x + b4);
            float v = __int_as_float(ee.y);
            a0 += v * bf2f((unsigned short)u);
            a1 += v * bf2f((unsigned short)(u >> 16));
        }
        for (; tB < eB; ++tB) {
            i32x2 ee = cv[tB];
            unsigned int u = *(const unsigned int*)(hbase + ee.x + b4);
            float v = __int_as_float(ee.y);
            c0 += v * bf2f((unsigned short)u);
            c1 += v * bf2f((unsigned short)(u >> 16));
        }
        *(unsigned int*)((char*)ph + ((size_t)rowA << 8) + b4)
            = (unsigned int)f2bf(a0) | ((unsigned int)f2bf(a1) << 16);
        if (hasB)
            *(unsigned int*)((char*)ph + ((size_t)rowB << 8) + b4)
                = (unsigned int)f2bf(c0) | ((unsigned int)f2bf(c1) << 16);
    }
}

// ======== GEMM building blocks (LDS slot-swizzle, rule 21) ========
// Single A plane, W hi-only: 1 MFMA per tile.
__device__ __forceinline__ void dense4(
    const unsigned short* r0, const unsigned short* wf0, f32x4 (&acc)[2][4],
    s16x8 (&b0)[4], int lrA, int lrB, int q, int xr, bool pf_last)
{
#pragma unroll
    for (int ch = 0; ch < 4; ++ch) {
        s16x8 nb0[4];
        const bool pf = (ch < 3) || pf_last;
        if (pf) {
            const unsigned short* nwp = wf0 + (size_t)(ch + 1) * 4096;
#pragma unroll
            for (int nt = 0; nt < 4; ++nt) nb0[nt] = LD8(nwp + nt * 512);
        }
        const int sl = (((ch * 4 + q) ^ xr) << 3);
        s16x8 aH0 = LD8(r0 + lrA * 128 + sl);
        s16x8 aH1 = LD8(r0 + lrB * 128 + sl);
#pragma unroll
        for (int nt = 0; nt < 4; ++nt) {
            acc[0][nt] = __builtin_amdgcn_mfma_f32_16x16x32_bf16(aH0, b0[nt], acc[0][nt], 0, 0, 0);
            acc[1][nt] = __builtin_amdgcn_mfma_f32_16x16x32_bf16(aH1, b0[nt], acc[1][nt], 0, 0, 0);
        }
        if (pf) {
#pragma unroll
            for (int nt = 0; nt < 4; ++nt) b0[nt] = nb0[nt];
        }
    }
}

// ---------------- GEMM: 128-row tile, 8 waves, 391 blocks. Single-bf16 A and
// W. LAP variant prefetches all 8 prop A-fragments into registers at kernel
// start. AVG-j1 prefetches its 8 res fragments. A-hi staged in LDS (32KB);
// epilogue fp32 tile overlays.
template<bool LAP>
__global__ __launch_bounds__(512, 4) void gemm_fused_kernel(
    const unsigned short* __restrict__ Ah,
    const unsigned short* __restrict__ Ph,
    const unsigned short* __restrict__ Wf, const float* __restrict__ bias,
    const float* __restrict__ res, float* __restrict__ out,
    unsigned short* __restrict__ Oh,
    const float* __restrict__ mask, float* __restrict__ accp,
    const float* __restrict__ accv, const float* __restrict__ Wb,
    const float* __restrict__ denom, int n)
{
    __shared__ __align__(16) char smem[69632];     // A-hi 32K; fp32 tile overlay 67.6K
    __shared__ float csum[128];
    __shared__ float partial[512];
    __shared__ float bias_s[128];
    unsigned short* r0 = (unsigned short*)smem;
    float* tile = (float*)smem;

    const int tid = threadIdx.x;
    const int m_base = blockIdx.x * 128;
    const int wid = tid >> 6, lane = tid & 63;
    const int wm = wid & 3, wn = wid >> 2;         // row quarter / col half
    const int q = lane >> 4, c16 = lane & 15;
    const int lrA = wm * 32 + c16, lrB = lrA + 16;
    const int xr = lrA & 7;

    // ---- stage hi->r0 (swizzled source, linear LDS dest) ----
    {
        const int lr = tid >> 4, slot = tid & 15;
#pragma unroll
        for (int k = 0; k < 4; ++k) {
            int row = k * 32 + lr;
            int ss = (slot ^ (row & 7)) * 8;
            gload_lds16(Ah + (size_t)(m_base + row) * CH + ss,
                        r0 + k * 4096 + tid * 8);
        }
    }
    // prop fragments issued now (in-order vmcnt: complete by dense phase)
    const int poff0 = (m_base + lrA) * CH + q * 8;
    const int poff1 = poff0 + 16 * CH;
    s16x8 pcA[4], pcB[4];
    if (LAP) {
#pragma unroll
        for (int cc = 0; cc < 4; ++cc) {
            pcA[cc] = LD8(Ph + poff0 + cc * 32);
            pcB[cc] = LD8(Ph + poff1 + cc * 32);
        }
    }
    // avg-j1: res fragments issued now too (complete by the flush)
    const int c4 = (tid & 31) << 2;
    f32x4 rv[8];
    if (!LAP && res) {
#pragma unroll
        for (int k = 0; k < 8; ++k) {
            int row = (tid + k * 512) >> 5;
            rv[k] = *(const f32x4*)(res + (size_t)(m_base + row) * CH + c4);
        }
    }

    if (tid < 128) bias_s[tid] = bias[tid];
    if (!LAP) {   // avg-step bias2 GEMV from prev-dispatch acc slot
        float rden = 1.f / denom[0];
        int c = tid & 127, h = tid >> 7;           // h in 0..3, 32 k's each
        float o = 0.f;
#pragma unroll 8
        for (int k = h * 32; k < h * 32 + 32; ++k) o += accv[k] * Wb[(size_t)k * CH + c];
        partial[tid] = o * rden;
    }

    f32x4 acc[2][4];
#pragma unroll
    for (int a = 0; a < 2; a++)
#pragma unroll
        for (int b = 0; b < 4; b++) acc[a][b] = (f32x4){0.f, 0.f, 0.f, 0.f};

    const unsigned short* wf0 = Wf + wn * 2048 + lane * 8;
    s16x8 b0[4];
#pragma unroll
    for (int nt = 0; nt < 4; ++nt) b0[nt] = LD8(wf0 + nt * 512);
    __syncthreads();                   // staging drained; bias/partial visible
    if (!LAP && tid < 128)
        bias_s[tid] += partial[tid] + partial[tid + 128]
                     + partial[tid + 256] + partial[tid + 384];

    dense4(r0, wf0, acc, b0, lrA, lrB, q, xr, LAP);

    if (LAP) {
        // ---- prop chunks 4..7: A in registers; B one chunk ahead ----
#pragma unroll
        for (int cc = 0; cc < 4; ++cc) {
            s16x8 nb0[4];
            if (cc < 3) {
                const unsigned short* nwp = wf0 + (size_t)(5 + cc) * 4096;
#pragma unroll
                for (int nt = 0; nt < 4; ++nt) nb0[nt] = LD8(nwp + nt * 512);
            }
#pragma unroll
            for (int nt = 0; nt < 4; ++nt) {
                acc[0][nt] = __builtin_amdgcn_mfma_f32_16x16x32_bf16(
                    pcA[cc], b0[nt], acc[0][nt], 0, 0, 0);
                acc[1][nt] = __builtin_amdgcn_mfma_f32_16x16x32_bf16(
                    pcB[cc], b0[nt], acc[1][nt], 0, 0, 0);
            }
            if (cc < 3) {
#pragma unroll
                for (int nt = 0; nt < 4; ++nt) b0[nt] = nb0[nt];
            }
        }
    }

    // ---- epilogue: fp32 tile overlays A staging ----
    if (accp && tid < 128) csum[tid] = 0.f;
    __syncthreads();
#pragma unroll
    for (int mt = 0; mt < 2; ++mt)
#pragma unroll
        for (int nt = 0; nt < 4; ++nt) {
            int col = wn * 64 + nt * 16 + c16;
            float bv = bias_s[col];
            int lrow = wm * 32 + mt * 16 + q * 4;
#pragma unroll
            for (int r = 0; r < 4; ++r)
                tile[(lrow + r) * 132 + col] = acc[mt][nt][r] + bv;
        }
    __syncthreads();

    float colsum[4] = {0.f, 0.f, 0.f, 0.f};
#pragma unroll
    for (int k = 0; k < 8; ++k) {
        int e4 = tid + k * 512;
        int row = e4 >> 5;
        int grow = m_base + row;
        if (grow < n) {
            f32x4 v = *(const f32x4*)&tile[row * 132 + c4];
            size_t o4 = (size_t)grow * CH + c4;
            if (res) {
                if (!LAP) v = v + rv[k];
                else      v = v + *(const f32x4*)(res + o4);
            }
            if (out) *(f32x4*)(out + o4) = v;
            float e0 = eluf(v[0]), e1 = eluf(v[1]), e2 = eluf(v[2]), e3 = eluf(v[3]);
            u16x4 hv = {f2bf(e0), f2bf(e1), f2bf(e2), f2bf(e3)};
            *(u16x4*)(Oh + o4) = hv;
            if (accp) {
                float mk = mask[grow];
                colsum[0] += mk * e0; colsum[1] += mk * e1;
                colsum[2] += mk * e2; colsum[3] += mk * e3;
            }
        }
    }
    if (accp) {
#pragma unroll
        for (int jj = 0; jj < 4; ++jj) atomicAdd(&csum[c4 + jj], colsum[jj]);
        __syncthreads();
        if (tid < 128) atomicAdd(&accp[tid], csum[tid]);
    }
}

// ---------------- final head ----------------
__global__ __launch_bounds__(256) void final_kernel(
    const unsigned short* __restrict__ hh,
    const float* __restrict__ W2, const float* __restrict__ b2,
    const float* __restrict__ in, float* __restrict__ out, int n)
{
    int wave = (blockIdx.x * blockDim.x + threadIdx.x) >> 6;
    int lane = threadIdx.x & 63;
    int stride = gridDim.x * 4;
    for (int row = wave; row < n; row += stride) {
        size_t i1 = (size_t)row * CH + lane;
        float v = bf2f(hh[i1]) * W2[lane] + bf2f(hh[i1 + 64]) * W2[64 + lane];
#pragma unroll
        for (int off = 32; off > 0; off >>= 1) v += __shfl_down(v, off, 64);
        if (lane == 0) out[row] = v + b2[0] + in[(size_t)row * 3];
    }
}

extern "C" void kernel_launch(void* const* d_in, const int* in_sizes, int n_in,
                              void* d_out, int out_size, void* d_ws, size_t ws_size,
                              hipStream_t stream)
{
    const int*   L_row   = (const int*)d_in[0];
    const int*   L_col   = (const int*)d_in[1];
    const float* L_val   = (const float*)d_in[2];
    const float* mask    = (const float*)d_in[3];
    const float* inputs  = (const float*)d_in[4];
    const float* conv1_W = (const float*)d_in[5];
    const float* conv1_b = (const float*)d_in[6];
    const float* blocks_W = (const float*)d_in[7];
    const float* blocks_b = (const float*)d_in[8];
    const float* conv2_W = (const float*)d_in[9];
    const float* conv2_b = (const float*)d_in[10];
    float* out = (float*)d_out;

    const int N = N_NODES, E = N_EDGES;
    const size_t NF = (size_t)N * CH;
    const int NPAD = 50048;
    const int NB = (N + 1023) / 1024;

    float* ws = (float*)d_ws;
    float* x0 = ws;
    float* x1 = x0 + NF;
    unsigned short* hbh0 = (unsigned short*)(x1 + NF);
    unsigned short* hbl0 = hbh0 + NF;                   // unused (layout keep)
    unsigned short* hbh1 = hbl0 + NF;
    unsigned short* hbl1 = hbh1 + NF;                   // unused (layout keep)
    unsigned short* ph   = hbl1 + NF;                   // prop hi plane (2*NF slack)
    int* cnt     = (int*)(ph + 2 * NF);
    int* cursor  = cnt + NPAD;
    int* row_ptr = cursor + NPAD;
    int* bsum    = row_ptr + NPAD;
    int* boff    = bsum + 64;
    i32x2* cv    = (i32x2*)(boff + 64);                 // interleaved {col<<8, val}
    float* acc_base = (float*)(cv + E);                 // 14 slots x 128
    float* denom    = acc_base + 14 * CH;
    unsigned short* wt = (unsigned short*)(denom + 16 + 160);  // 30*32768 shorts (hi only)

    zero_all_kernel<<<(2 * NPAD + 255) / 256, 256, 0, stream>>>(
        cnt, 2 * NPAD, acc_base, 14 * CH + 16);
    count_kernel<<<(E + 255) / 256, 256, 0, stream>>>(L_row, cnt, E);
    block_reduce_kernel<<<NB, 1024, 0, stream>>>(cnt, bsum, N);
    scan_small_kernel<<<1, 64, 0, stream>>>(bsum, boff, NB);
    block_scan_kernel<<<NB, 1024, 0, stream>>>(cnt, boff, row_ptr, N);
    fill_kernel<<<(E + 255) / 256, 256, 0, stream>>>(L_row, L_col, L_val, cursor,
                                                     row_ptr, cv, E);
    mask_sum_kernel<<<64, 256, 0, stream>>>(mask, denom, N);
    split_w_kernel<<<(30 * 32768 + 255) / 256, 256, 0, stream>>>(blocks_W, wt, 30 * 32768);

    conv1_kernel<<<(N * CH + 255) / 256, 256, 0, stream>>>(inputs, conv1_W, conv1_b,
                                                           x0, hbh0, N);

    float* xin = x0;
    float* xout = x1;

    for (int i = 0; i < N_LAYERS; ++i) {
        int s0 = i * 2, s1 = s0 + 1;
        if ((i & 1) == 0) {
            lap_kernel<<<LAP_BLOCKS, 256, 0, stream>>>(row_ptr, cv, hbh0, ph, N);
            gemm_fused_kernel<true><<<GB, 512, 0, stream>>>(
                hbh0, ph, wt + (size_t)s0 * 32768, blocks_b + (size_t)s0 * CH,
                nullptr, nullptr, hbh1, mask, nullptr,
                nullptr, nullptr, denom, N);
            lap_kernel<<<LAP_BLOCKS, 256, 0, stream>>>(row_ptr, cv, hbh1, ph, N);
            float* accp1 = (i < 14) ? acc_base + (size_t)i * CH : nullptr;
            gemm_fused_kernel<true><<<GB, 512, 0, stream>>>(
                hbh1, ph, wt + (size_t)s1 * 32768, blocks_b + (size_t)s1 * CH,
                xin, xout, hbh0, mask, accp1,
                nullptr, nullptr, denom, N);
        } else {
            gemm_fused_kernel<false><<<GB, 512, 0, stream>>>(
                hbh0, nullptr, wt + (size_t)s0 * 32768, blocks_b + (size_t)s0 * CH,
                nullptr, nullptr, hbh1, mask, acc_base + (size_t)i * CH,
                acc_base + (size_t)(i - 1) * CH,
                blocks_W + (size_t)s0 * 256 * CH + 128 * CH,
                denom, N);
            gemm_fused_kernel<false><<<GB, 512, 0, stream>>>(
                hbh1, nullptr, wt + (size_t)s1 * 32768, blocks_b + (size_t)s1 * CH,
                xin, xout, hbh0, mask, nullptr,
                acc_base + (size_t)i * CH,
                blocks_W + (size_t)s1 * 256 * CH + 128 * CH,
                denom, N);
        }
        float* t = xin; xin = xout; xout = t;
    }
    final_kernel<<<2048, 256, 0, stream>>>(hbh0, conv2_W, conv2_b, inputs, out, N);
}

// Round 20
// 1182.666 us; speedup vs baseline: 1.0178x; 1.0178x over previous
//
#include <hip/hip_runtime.h>
#include <hip/hip_bf16.h>

#define N_NODES 50000
#define N_EDGES 600000
#define CH 128
#define N_LAYERS 15
#define GB 391                      // gemm grid: 128-row tiles
#define LAP_BLOCKS 2048

typedef float f32x4 __attribute__((ext_vector_type(4)));
typedef short s16x8 __attribute__((ext_vector_type(8)));
typedef unsigned short u16x4 __attribute__((ext_vector_type(4)));
typedef int i32x2 __attribute__((ext_vector_type(2)));

#define LD8(p) (*(const s16x8*)(p))

__device__ __forceinline__ float eluf(float v) {
    return v > 0.f ? v : (__expf(v) - 1.f);
}
__device__ __forceinline__ unsigned short f2bf(float f) {
    unsigned int u = __float_as_uint(f);
    unsigned int r = (u + 0x7FFFu + ((u >> 16) & 1u)) >> 16;
    return (unsigned short)r;
}
__device__ __forceinline__ float bf2f(unsigned short h) {
    return __uint_as_float(((unsigned int)h) << 16);
}
__device__ __forceinline__ void gload_lds16(const unsigned short* g, unsigned short* l) {
    __builtin_amdgcn_global_load_lds(
        (const __attribute__((address_space(1))) unsigned int*)g,
        (__attribute__((address_space(3))) unsigned int*)l, 16, 0, 0);
}

// ---------------- conv1: writes bf16 x plane + bf16 elu plane ----------------
__global__ __launch_bounds__(256) void conv1_kernel(
    const float* __restrict__ in, const float* __restrict__ W1,
    const float* __restrict__ b1, unsigned short* __restrict__ xb,
    unsigned short* __restrict__ hbh, int n)
{
    int idx = blockIdx.x * blockDim.x + threadIdx.x;
    if (idx >= n * CH) return;
    int node = idx >> 7;
    int c = idx & 127;
    float o = b1[c]
            + in[(size_t)node * 3 + 0] * W1[0 * CH + c]
            + in[(size_t)node * 3 + 1] * W1[1 * CH + c]
            + in[(size_t)node * 3 + 2] * W1[2 * CH + c];
    xb[idx] = f2bf(o);
    hbh[idx] = f2bf(eluf(o));
}

// ---------------- combined zero helper ----------------
__global__ __launch_bounds__(256) void zero_all_kernel(
    int* __restrict__ pi, int ni, float* __restrict__ pf, int nf)
{
    int i = blockIdx.x * blockDim.x + threadIdx.x;
    if (i < ni) pi[i] = 0;
    if (i < nf) pf[i] = 0.f;
}

// ---------------- CSR build ----------------
__global__ __launch_bounds__(256) void count_kernel(
    const int* __restrict__ row, int* __restrict__ cnt, int e)
{
    int i = blockIdx.x * blockDim.x + threadIdx.x;
    if (i < e) atomicAdd(&cnt[row[i]], 1);
}

__global__ __launch_bounds__(1024) void block_reduce_kernel(
    const int* __restrict__ cnt, int* __restrict__ bsum, int n)
{
    __shared__ int sd[1024];
    int tid = threadIdx.x;
    int i = blockIdx.x * 1024 + tid;
    sd[tid] = (i < n) ? cnt[i] : 0;
    __syncthreads();
    for (int off = 512; off > 0; off >>= 1) {
        if (tid < off) sd[tid] += sd[tid + off];
        __syncthreads();
    }
    if (tid == 0) bsum[blockIdx.x] = sd[0];
}

__global__ __launch_bounds__(64) void scan_small_kernel(
    const int* __restrict__ bsum, int* __restrict__ boff, int nb)
{
    int lane = threadIdx.x;
    int orig = (lane < nb) ? bsum[lane] : 0;
    int v = orig;
#pragma unroll
    for (int d = 1; d < 64; d <<= 1) {
        int t = __shfl_up(v, d, 64);
        if (lane >= d) v += t;
    }
    if (lane < nb) boff[lane] = v - orig;  // exclusive
}

__global__ __launch_bounds__(1024) void block_scan_kernel(
    const int* __restrict__ cnt, const int* __restrict__ boff,
    int* __restrict__ row_ptr, int n)
{
    __shared__ int sd[1024];
    int tid = threadIdx.x;
    int i = blockIdx.x * 1024 + tid;
    sd[tid] = (i < n) ? cnt[i] : 0;
    __syncthreads();
    for (int off = 1; off < 1024; off <<= 1) {
        int t = (tid >= off) ? sd[tid - off] : 0;
        __syncthreads();
        sd[tid] += t;
        __syncthreads();
    }
    if (i < n) row_ptr[i + 1] = sd[tid] + boff[blockIdx.x];
    if (i == 0) row_ptr[0] = 0;
}

// cv[dst] = {col byte-offset, val bits} — one 8B scatter per edge
__global__ __launch_bounds__(256) void fill_kernel(
    const int* __restrict__ row, const int* __restrict__ col,
    const float* __restrict__ val, int* __restrict__ cursor,
    const int* __restrict__ row_ptr, i32x2* __restrict__ cv, int e)
{
    int i = blockIdx.x * blockDim.x + threadIdx.x;
    if (i >= e) return;
    int r = row[i];
    int pos = atomicAdd(&cursor[r], 1);
    int dst = row_ptr[r] + pos;
    i32x2 v = { col[i] << 8, __float_as_int(val[i]) };
    cv[dst] = v;
}

// ---------------- mask denominator ----------------
__global__ __launch_bounds__(256) void mask_sum_kernel(
    const float* __restrict__ mask, float* __restrict__ denom, int n)
{
    __shared__ float sd[256];
    int tid = threadIdx.x;
    float s = 0.f;
    for (int i = blockIdx.x * 256 + tid; i < n; i += gridDim.x * 256) s += mask[i];
    sd[tid] = s;
    __syncthreads();
    for (int off = 128; off > 0; off >>= 1) {
        if (tid < off) sd[tid] += sd[tid + off];
        __syncthreads();
    }
    if (tid == 0) atomicAdd(denom, sd[0]);
}

// ---- W pre-split into MFMA-fragment order — HI PLANE ONLY (R14 win) ----
__global__ __launch_bounds__(256) void split_w_kernel(
    const float* __restrict__ W, unsigned short* __restrict__ Wf, int total)
{
    int id = blockIdx.x * 256 + threadIdx.x;
    if (id >= total) return;
    int s = id >> 15;
    int rem = id & 32767;
    int k = rem >> 7;
    int nn = rem & 127;
    unsigned short hi = f2bf(W[id]);
    int c   = k >> 5;
    int kin = k & 31;
    int q   = kin >> 3;
    int ko  = kin & 7;
    int nt  = nn >> 4;
    int c16 = nn & 15;
    int lane = q * 16 + c16;
    size_t base = (size_t)s * 32768 + (size_t)c * 4096 + (size_t)nt * 512
                + (size_t)lane * 8 + ko;
    Wf[base] = hi;
}

// ---------------- Laplacian: prop[row,:] = sum_e val * hb[col,:]
// R18-validated: one wave per row, single 256B VMEM per edge (64 lanes x 4B
// = 2 bf16 channels/lane), 8192 row-processors, packed uint ph store.
__global__ __launch_bounds__(256) void lap_kernel(
    const int* __restrict__ rp, const i32x2* __restrict__ cv,
    const unsigned short* __restrict__ hb,
    unsigned short* __restrict__ ph, int n)
{
    int unit = (blockIdx.x * 256 + threadIdx.x) >> 6;    // 0..8191
    int lane = threadIdx.x & 63;
    const int b4 = lane << 2;                            // byte offset in row
    const char* hbase = (const char*)hb;
    for (int row = unit; row < n; row += LAP_BLOCKS * 4) {
        int s = rp[row], e = rp[row + 1];
        float a0 = 0.f, a1 = 0.f;
        int t = s;
        for (; t + 8 <= e; t += 8) {
            i32x2 e0 = cv[t],     e1 = cv[t + 1], e2 = cv[t + 2], e3 = cv[t + 3];
            i32x2 e4 = cv[t + 4], e5 = cv[t + 5], e6 = cv[t + 6], e7 = cv[t + 7];
            unsigned int u0 = *(const unsigned int*)(hbase + e0.x + b4);
            unsigned int u1 = *(const unsigned int*)(hbase + e1.x + b4);
            unsigned int u2 = *(const unsigned int*)(hbase + e2.x + b4);
            unsigned int u3 = *(const unsigned int*)(hbase + e3.x + b4);
            unsigned int u4 = *(const unsigned int*)(hbase + e4.x + b4);
            unsigned int u5 = *(const unsigned int*)(hbase + e5.x + b4);
            unsigned int u6 = *(const unsigned int*)(hbase + e6.x + b4);
            unsigned int u7 = *(const unsigned int*)(hbase + e7.x + b4);
            float v0 = __int_as_float(e0.y), v1 = __int_as_float(e1.y);
            float v2 = __int_as_float(e2.y), v3 = __int_as_float(e3.y);
            float v4 = __int_as_float(e4.y), v5 = __int_as_float(e5.y);
            float v6 = __int_as_float(e6.y), v7 = __int_as_float(e7.y);
            a0 += v0 * bf2f((unsigned short)u0) + v1 * bf2f((unsigned short)u1)
                + v2 * bf2f((unsigned short)u2) + v3 * bf2f((unsigned short)u3)
                + v4 * bf2f((unsigned short)u4) + v5 * bf2f((unsigned short)u5)
                + v6 * bf2f((unsigned short)u6) + v7 * bf2f((unsigned short)u7);
            a1 += v0 * bf2f((unsigned short)(u0 >> 16)) + v1 * bf2f((unsigned short)(u1 >> 16))
                + v2 * bf2f((unsigned short)(u2 >> 16)) + v3 * bf2f((unsigned short)(u3 >> 16))
                + v4 * bf2f((unsigned short)(u4 >> 16)) + v5 * bf2f((unsigned short)(u5 >> 16))
                + v6 * bf2f((unsigned short)(u6 >> 16)) + v7 * bf2f((unsigned short)(u7 >> 16));
        }
        for (; t + 4 <= e; t += 4) {
            i32x2 e0 = cv[t], e1 = cv[t + 1], e2 = cv[t + 2], e3 = cv[t + 3];
            unsigned int u0 = *(const unsigned int*)(hbase + e0.x + b4);
            unsigned int u1 = *(const unsigned int*)(hbase + e1.x + b4);
            unsigned int u2 = *(const unsigned int*)(hbase + e2.x + b4);
            unsigned int u3 = *(const unsigned int*)(hbase + e3.x + b4);
            float v0 = __int_as_float(e0.y), v1 = __int_as_float(e1.y);
            float v2 = __int_as_float(e2.y), v3 = __int_as_float(e3.y);
            a0 += v0 * bf2f((unsigned short)u0) + v1 * bf2f((unsigned short)u1)
                + v2 * bf2f((unsigned short)u2) + v3 * bf2f((unsigned short)u3);
            a1 += v0 * bf2f((unsigned short)(u0 >> 16)) + v1 * bf2f((unsigned short)(u1 >> 16))
                + v2 * bf2f((unsigned short)(u2 >> 16)) + v3 * bf2f((unsigned short)(u3 >> 16));
        }
        for (; t < e; ++t) {
            i32x2 ee = cv[t];
            unsigned int u = *(const unsigned int*)(hbase + ee.x + b4);
            float v = __int_as_float(ee.y);
            a0 += v * bf2f((unsigned short)u);
            a1 += v * bf2f((unsigned short)(u >> 16));
        }
        *(unsigned int*)((char*)ph + ((size_t)row << 8) + b4)
            = (unsigned int)f2bf(a0) | ((unsigned int)f2bf(a1) << 16);
    }
}

// ======== GEMM building blocks (LDS slot-swizzle, rule 21) ========
// Single A plane, W hi-only: 1 MFMA per tile.
__device__ __forceinline__ void dense4(
    const unsigned short* r0, const unsigned short* wf0, f32x4 (&acc)[2][4],
    s16x8 (&b0)[4], int lrA, int lrB, int q, int xr, bool pf_last)
{
#pragma unroll
    for (int ch = 0; ch < 4; ++ch) {
        s16x8 nb0[4];
        const bool pf = (ch < 3) || pf_last;
        if (pf) {
            const unsigned short* nwp = wf0 + (size_t)(ch + 1) * 4096;
#pragma unroll
            for (int nt = 0; nt < 4; ++nt) nb0[nt] = LD8(nwp + nt * 512);
        }
        const int sl = (((ch * 4 + q) ^ xr) << 3);
        s16x8 aH0 = LD8(r0 + lrA * 128 + sl);
        s16x8 aH1 = LD8(r0 + lrB * 128 + sl);
#pragma unroll
        for (int nt = 0; nt < 4; ++nt) {
            acc[0][nt] = __builtin_amdgcn_mfma_f32_16x16x32_bf16(aH0, b0[nt], acc[0][nt], 0, 0, 0);
            acc[1][nt] = __builtin_amdgcn_mfma_f32_16x16x32_bf16(aH1, b0[nt], acc[1][nt], 0, 0, 0);
        }
        if (pf) {
#pragma unroll
            for (int nt = 0; nt < 4; ++nt) b0[nt] = nb0[nt];
        }
    }
}

// ---------------- GEMM: 128-row tile, 8 waves, 391 blocks. Single-bf16 A, W,
// and (R20) RESIDUAL: res/out are bf16 planes (backbone demoted — saves
// 384MB of fp32 traffic across 15 layers). LAP variant prefetches all 8 prop
// A-fragments; AVG-j1 prefetches its 8 bf16 res fragments. A-hi staged in
// LDS (32KB); epilogue fp32 tile overlays.
template<bool LAP>
__global__ __launch_bounds__(512, 4) void gemm_fused_kernel(
    const unsigned short* __restrict__ Ah,
    const unsigned short* __restrict__ Ph,
    const unsigned short* __restrict__ Wf, const float* __restrict__ bias,
    const unsigned short* __restrict__ res, unsigned short* __restrict__ out,
    unsigned short* __restrict__ Oh,
    const float* __restrict__ mask, float* __restrict__ accp,
    const float* __restrict__ accv, const float* __restrict__ Wb,
    const float* __restrict__ denom, int n)
{
    __shared__ __align__(16) char smem[69632];     // A-hi 32K; fp32 tile overlay 67.6K
    __shared__ float csum[128];
    __shared__ float partial[512];
    __shared__ float bias_s[128];
    unsigned short* r0 = (unsigned short*)smem;
    float* tile = (float*)smem;

    const int tid = threadIdx.x;
    const int m_base = blockIdx.x * 128;
    const int wid = tid >> 6, lane = tid & 63;
    const int wm = wid & 3, wn = wid >> 2;         // row quarter / col half
    const int q = lane >> 4, c16 = lane & 15;
    const int lrA = wm * 32 + c16, lrB = lrA + 16;
    const int xr = lrA & 7;

    // ---- stage hi->r0 (swizzled source, linear LDS dest) ----
    {
        const int lr = tid >> 4, slot = tid & 15;
#pragma unroll
        for (int k = 0; k < 4; ++k) {
            int row = k * 32 + lr;
            int ss = (slot ^ (row & 7)) * 8;
            gload_lds16(Ah + (size_t)(m_base + row) * CH + ss,
                        r0 + k * 4096 + tid * 8);
        }
    }
    // prop fragments issued now (in-order vmcnt: complete by dense phase)
    const int poff0 = (m_base + lrA) * CH + q * 8;
    const int poff1 = poff0 + 16 * CH;
    s16x8 pcA[4], pcB[4];
    if (LAP) {
#pragma unroll
        for (int cc = 0; cc < 4; ++cc) {
            pcA[cc] = LD8(Ph + poff0 + cc * 32);
            pcB[cc] = LD8(Ph + poff1 + cc * 32);
        }
    }
    // avg-j1: bf16 res fragments issued now too (complete by the flush)
    const int c4 = (tid & 31) << 2;
    u16x4 rv16[8];
    if (!LAP && res) {
#pragma unroll
        for (int k = 0; k < 8; ++k) {
            int row = (tid + k * 512) >> 5;
            rv16[k] = *(const u16x4*)(res + (size_t)(m_base + row) * CH + c4);
        }
    }

    if (tid < 128) bias_s[tid] = bias[tid];
    if (!LAP) {   // avg-step bias2 GEMV from prev-dispatch acc slot
        float rden = 1.f / denom[0];
        int c = tid & 127, h = tid >> 7;           // h in 0..3, 32 k's each
        float o = 0.f;
#pragma unroll 8
        for (int k = h * 32; k < h * 32 + 32; ++k) o += accv[k] * Wb[(size_t)k * CH + c];
        partial[tid] = o * rden;
    }

    f32x4 acc[2][4];
#pragma unroll
    for (int a = 0; a < 2; a++)
#pragma unroll
        for (int b = 0; b < 4; b++) acc[a][b] = (f32x4){0.f, 0.f, 0.f, 0.f};

    const unsigned short* wf0 = Wf + wn * 2048 + lane * 8;
    s16x8 b0[4];
#pragma unroll
    for (int nt = 0; nt < 4; ++nt) b0[nt] = LD8(wf0 + nt * 512);
    __syncthreads();                   // staging drained; bias/partial visible
    if (!LAP && tid < 128)
        bias_s[tid] += partial[tid] + partial[tid + 128]
                     + partial[tid + 256] + partial[tid + 384];

    dense4(r0, wf0, acc, b0, lrA, lrB, q, xr, LAP);

    if (LAP) {
        // ---- prop chunks 4..7: A in registers; B one chunk ahead ----
#pragma unroll
        for (int cc = 0; cc < 4; ++cc) {
            s16x8 nb0[4];
            if (cc < 3) {
                const unsigned short* nwp = wf0 + (size_t)(5 + cc) * 4096;
#pragma unroll
                for (int nt = 0; nt < 4; ++nt) nb0[nt] = LD8(nwp + nt * 512);
            }
#pragma unroll
            for (int nt = 0; nt < 4; ++nt) {
                acc[0][nt] = __builtin_amdgcn_mfma_f32_16x16x32_bf16(
                    pcA[cc], b0[nt], acc[0][nt], 0, 0, 0);
                acc[1][nt] = __builtin_amdgcn_mfma_f32_16x16x32_bf16(
                    pcB[cc], b0[nt], acc[1][nt], 0, 0, 0);
            }
            if (cc < 3) {
#pragma unroll
                for (int nt = 0; nt < 4; ++nt) b0[nt] = nb0[nt];
            }
        }
    }

    // ---- epilogue: fp32 tile overlays A staging ----
    if (accp && tid < 128) csum[tid] = 0.f;
    __syncthreads();
#pragma unroll
    for (int mt = 0; mt < 2; ++mt)
#pragma unroll
        for (int nt = 0; nt < 4; ++nt) {
            int col = wn * 64 + nt * 16 + c16;
            float bv = bias_s[col];
            int lrow = wm * 32 + mt * 16 + q * 4;
#pragma unroll
            for (int r = 0; r < 4; ++r)
                tile[(lrow + r) * 132 + col] = acc[mt][nt][r] + bv;
        }
    __syncthreads();

    float colsum[4] = {0.f, 0.f, 0.f, 0.f};
#pragma unroll
    for (int k = 0; k < 8; ++k) {
        int e4 = tid + k * 512;
        int row = e4 >> 5;
        int grow = m_base + row;
        if (grow < n) {
            f32x4 v = *(const f32x4*)&tile[row * 132 + c4];
            size_t o4 = (size_t)grow * CH + c4;
            if (res) {
                u16x4 rb = (!LAP) ? rv16[k] : *(const u16x4*)(res + o4);
                v[0] += bf2f(rb[0]); v[1] += bf2f(rb[1]);
                v[2] += bf2f(rb[2]); v[3] += bf2f(rb[3]);
            }
            if (out) {
                u16x4 ob = {f2bf(v[0]), f2bf(v[1]), f2bf(v[2]), f2bf(v[3])};
                *(u16x4*)(out + o4) = ob;
            }
            float e0 = eluf(v[0]), e1 = eluf(v[1]), e2 = eluf(v[2]), e3 = eluf(v[3]);
            u16x4 hv = {f2bf(e0), f2bf(e1), f2bf(e2), f2bf(e3)};
            *(u16x4*)(Oh + o4) = hv;
            if (accp) {
                float mk = mask[grow];
                colsum[0] += mk * e0; colsum[1] += mk * e1;
                colsum[2] += mk * e2; colsum[3] += mk * e3;
            }
        }
    }
    if (accp) {
#pragma unroll
        for (int jj = 0; jj < 4; ++jj) atomicAdd(&csum[c4 + jj], colsum[jj]);
        __syncthreads();
        if (tid < 128) atomicAdd(&accp[tid], csum[tid]);
    }
}

// ---------------- final head ----------------
__global__ __launch_bounds__(256) void final_kernel(
    const unsigned short* __restrict__ hh,
    const float* __restrict__ W2, const float* __restrict__ b2,
    const float* __restrict__ in, float* __restrict__ out, int n)
{
    int wave = (blockIdx.x * blockDim.x + threadIdx.x) >> 6;
    int lane = threadIdx.x & 63;
    int stride = gridDim.x * 4;
    for (int row = wave; row < n; row += stride) {
        size_t i1 = (size_t)row * CH + lane;
        float v = bf2f(hh[i1]) * W2[lane] + bf2f(hh[i1 + 64]) * W2[64 + lane];
#pragma unroll
        for (int off = 32; off > 0; off >>= 1) v += __shfl_down(v, off, 64);
        if (lane == 0) out[row] = v + b2[0] + in[(size_t)row * 3];
    }
}

extern "C" void kernel_launch(void* const* d_in, const int* in_sizes, int n_in,
                              void* d_out, int out_size, void* d_ws, size_t ws_size,
                              hipStream_t stream)
{
    const int*   L_row   = (const int*)d_in[0];
    const int*   L_col   = (const int*)d_in[1];
    const float* L_val   = (const float*)d_in[2];
    const float* mask    = (const float*)d_in[3];
    const float* inputs  = (const float*)d_in[4];
    const float* conv1_W = (const float*)d_in[5];
    const float* conv1_b = (const float*)d_in[6];
    const float* blocks_W = (const float*)d_in[7];
    const float* blocks_b = (const float*)d_in[8];
    const float* conv2_W = (const float*)d_in[9];
    const float* conv2_b = (const float*)d_in[10];
    float* out = (float*)d_out;

    const int N = N_NODES, E = N_EDGES;
    const size_t NF = (size_t)N * CH;
    const int NPAD = 50048;
    const int NB = (N + 1023) / 1024;

    float* ws = (float*)d_ws;
    float* x0 = ws;                                     // unused (layout keep)
    float* x1 = x0 + NF;                                // unused (layout keep)
    unsigned short* hbh0 = (unsigned short*)(x1 + NF);
    unsigned short* xb0  = hbh0 + NF;                   // bf16 residual, slot 0
    unsigned short* hbh1 = xb0 + NF;
    unsigned short* xb1  = hbh1 + NF;                   // bf16 residual, slot 1
    unsigned short* ph   = xb1 + NF;                    // prop hi plane (2*NF slack)
    int* cnt     = (int*)(ph + 2 * NF);
    int* cursor  = cnt + NPAD;
    int* row_ptr = cursor + NPAD;
    int* bsum    = row_ptr + NPAD;
    int* boff    = bsum + 64;
    i32x2* cv    = (i32x2*)(boff + 64);                 // interleaved {col<<8, val}
    float* acc_base = (float*)(cv + E);                 // 14 slots x 128
    float* denom    = acc_base + 14 * CH;
    unsigned short* wt = (unsigned short*)(denom + 16 + 160);  // 30*32768 shorts (hi only)

    zero_all_kernel<<<(2 * NPAD + 255) / 256, 256, 0, stream>>>(
        cnt, 2 * NPAD, acc_base, 14 * CH + 16);
    count_kernel<<<(E + 255) / 256, 256, 0, stream>>>(L_row, cnt, E);
    block_reduce_kernel<<<NB, 1024, 0, stream>>>(cnt, bsum, N);
    scan_small_kernel<<<1, 64, 0, stream>>>(bsum, boff, NB);
    block_scan_kernel<<<NB, 1024, 0, stream>>>(cnt, boff, row_ptr, N);
    fill_kernel<<<(E + 255) / 256, 256, 0, stream>>>(L_row, L_col, L_val, cursor,
                                                     row_ptr, cv, E);
    mask_sum_kernel<<<64, 256, 0, stream>>>(mask, denom, N);
    split_w_kernel<<<(30 * 32768 + 255) / 256, 256, 0, stream>>>(blocks_W, wt, 30 * 32768);

    conv1_kernel<<<(N * CH + 255) / 256, 256, 0, stream>>>(inputs, conv1_W, conv1_b,
                                                           xb0, hbh0, N);

    unsigned short* xin = xb0;
    unsigned short* xout = xb1;

    for (int i = 0; i < N_LAYERS; ++i) {
        int s0 = i * 2, s1 = s0 + 1;
        if ((i & 1) == 0) {
            lap_kernel<<<LAP_BLOCKS, 256, 0, stream>>>(row_ptr, cv, hbh0, ph, N);
            gemm_fused_kernel<true><<<GB, 512, 0, stream>>>(
                hbh0, ph, wt + (size_t)s0 * 32768, blocks_b + (size_t)s0 * CH,
                nullptr, nullptr, hbh1, mask, nullptr,
                nullptr, nullptr, denom, N);
            lap_kernel<<<LAP_BLOCKS, 256, 0, stream>>>(row_ptr, cv, hbh1, ph, N);
            float* accp1 = (i < 14) ? acc_base + (size_t)i * CH : nullptr;
            gemm_fused_kernel<true><<<GB, 512, 0, stream>>>(
                hbh1, ph, wt + (size_t)s1 * 32768, blocks_b + (size_t)s1 * CH,
                xin, xout, hbh0, mask, accp1,
                nullptr, nullptr, denom, N);
        } else {
            gemm_fused_kernel<false><<<GB, 512, 0, stream>>>(
                hbh0, nullptr, wt + (size_t)s0 * 32768, blocks_b + (size_t)s0 * CH,
                nullptr, nullptr, hbh1, mask, acc_base + (size_t)i * CH,
                acc_base + (size_t)(i - 1) * CH,
                blocks_W + (size_t)s0 * 256 * CH + 128 * CH,
                denom, N);
            gemm_fused_kernel<false><<<GB, 512, 0, stream>>>(
                hbh1, nullptr, wt + (size_t)s1 * 32768, blocks_b + (size_t)s1 * CH,
                xin, xout, hbh0, mask, nullptr,
                acc_base + (size_t)i * CH,
                blocks_W + (size_t)s1 * 256 * CH + 128 * CH,
                denom, N);
        }
        unsigned short* t = xin; xin = xout; xout = t;
    }
    final_kernel<<<2048, 256, 0, stream>>>(hbh0, conv2_W, conv2_b, inputs, out, N);
}